// Round 2
// baseline (1087.348 us; speedup 1.0000x reference)
//
#include <hip/hip_runtime.h>
#include <math.h>

#define N_NODES 100000
#define N_EDGES 1600000
#define DIM 128
#define EIGD 32
#define CS_EPS 1e-8f

// ---- workspace layout (bytes) ----
static const size_t OFF_SE     = 0;          // E float2 {int col, float adj} CSR-ordered
static const size_t OFF_COUNT  = 12800000;   // N int
static const size_t OFF_OFFS   = 13200000;   // N+1 int
static const size_t OFF_CURSOR = 13600016;   // N int
static const size_t OFF_ME     = 14000016;   // N float
static const size_t OFF_SCAL   = 14400016;   // 4 float (Sab,Saa,Sbb,c)

__global__ void k0_init(const float* __restrict__ motif_w,
                        const int* __restrict__ motif_ids,
                        float* __restrict__ me, int* __restrict__ count,
                        float* __restrict__ scal) {
    int i = blockIdx.x * blockDim.x + threadIdx.x;
    if (i < N_NODES) {
        me[i] = motif_w[motif_ids[i]];
        count[i] = 0;
    }
    if (i < 4) scal[i] = 0.f;
}

// Light edge pass: histogram count[row] + cosine-sim partial sums.
__global__ void __launch_bounds__(256) k1_hist(
        const int* __restrict__ row, const int* __restrict__ col,
        const float* __restrict__ me,
        int* __restrict__ count, float* __restrict__ scal) {
    int e = blockIdx.x * blockDim.x + threadIdx.x;
    float sab = 0.f, saa = 0.f, sbb = 0.f;
    if (e < N_EDGES) {
        int r = row[e], c = col[e];
        atomicAdd(&count[r], 1);
        float mr = me[r], mc = me[c];
        sab = mr * mc; saa = mr * mr; sbb = mc * mc;
    }
#pragma unroll
    for (int off = 32; off >= 1; off >>= 1) {
        sab += __shfl_xor(sab, off);
        saa += __shfl_xor(saa, off);
        sbb += __shfl_xor(sbb, off);
    }
    __shared__ float ls[3][4];
    int lane = threadIdx.x & 63, wid = threadIdx.x >> 6;
    if (lane == 0) { ls[0][wid] = sab; ls[1][wid] = saa; ls[2][wid] = sbb; }
    __syncthreads();
    if (threadIdx.x == 0) {
        float a = 0.f, b = 0.f, cc = 0.f;
#pragma unroll
        for (int i = 0; i < 4; i++) { a += ls[0][i]; b += ls[1][i]; cc += ls[2][i]; }
        atomicAdd(&scal[0], a);
        atomicAdd(&scal[1], b);
        atomicAdd(&scal[2], cc);
    }
}

// Single block: finalize scalar c = gamma*sim; exclusive-scan count -> offs/cursor.
__global__ void __launch_bounds__(1024) k2_scan(
        const float* __restrict__ gamma, float* __restrict__ scal,
        const int* __restrict__ count, int* __restrict__ offs,
        int* __restrict__ cursor) {
    const int t = threadIdx.x;
    if (t == 0) {
        float sab = scal[0], saa = scal[1], sbb = scal[2];
        float na = sqrtf(saa); if (na < CS_EPS) na = CS_EPS;
        float nb = sqrtf(sbb); if (nb < CS_EPS) nb = CS_EPS;
        scal[3] = gamma[0] * (sab / (na * nb));
    }
    const int CH = (N_NODES + 1023) / 1024;  // 98
    const int base = t * CH;
    int lsum = 0;
    for (int i = 0; i < CH; i++) {
        int idx = base + i;
        if (idx < N_NODES) lsum += count[idx];
    }
    __shared__ int sc[1024];
    sc[t] = lsum;
    __syncthreads();
    for (int off = 1; off < 1024; off <<= 1) {
        int vv = (t >= off) ? sc[t - off] : 0;
        __syncthreads();
        sc[t] += vv;
        __syncthreads();
    }
    int run = sc[t] - lsum;  // exclusive prefix at chunk start
    for (int i = 0; i < CH; i++) {
        int idx = base + i;
        if (idx < N_NODES) {
            offs[idx] = run;
            cursor[idx] = run;
            run += count[idx];
        }
    }
    if (t == 1023) offs[N_NODES] = sc[1023];
}

// Scatter edges into CSR order: se[pos] = {col (as float bits), adj}.
__global__ void __launch_bounds__(256) k3_scatter(
        const int* __restrict__ row, const int* __restrict__ col,
        const float* __restrict__ adj, int* __restrict__ cursor,
        float2* __restrict__ se) {
    int e = blockIdx.x * blockDim.x + threadIdx.x;
    if (e >= N_EDGES) return;
    int r = row[e];
    int pos = atomicAdd(&cursor[r], 1);
    se[pos] = make_float2(__int_as_float(col[e]), adj[e]);
}

// Fused flash-style per-row attention: one wave per row.
// q-row/eig-row in registers; 2 edges per iteration (32 lanes each, dim-parallel);
// online softmax on both branches; v accumulated dim-parallel across 64 lanes.
__global__ void __launch_bounds__(256) k4_flash(
        const float* __restrict__ q, const float* __restrict__ k,
        const float* __restrict__ eigs, const float* __restrict__ v,
        const float* __restrict__ lambda0, const int* __restrict__ offs,
        const float2* __restrict__ se, const float* __restrict__ scal,
        float* __restrict__ out) {
    const int tid  = threadIdx.x;
    const int lane = tid & 63;
    const int wid  = tid >> 6;
    const int r = blockIdx.x * 4 + wid;
    if (r >= N_NODES) return;
    const int l32  = lane & 31;
    const int half = lane >> 5;
    const float inv_sqrt_d = 0.08838834764831843f; // 1/sqrt(128)

    const int start = offs[r], end = offs[r + 1];
    if (end == start) {
        ((float2*)(out + (size_t)r * DIM))[lane] = make_float2(0.f, 0.f);
        return;
    }

    const float el0 = expf(lambda0[0]);
    const float cs  = scal[3];

    const float4 qv = ((const float4*)(q + (size_t)r * DIM))[l32];
    const float  er = eigs[(size_t)r * EIGD + l32];

    float m0 = -INFINITY, z0 = 0.f, m1 = -INFINITY, z1 = 0.f;
    float2 acc0 = make_float2(0.f, 0.f), acc1 = make_float2(0.f, 0.f);

    for (int base = start; base < end; base += 2) {
        int e = base + half;              // uniform per 32-lane group
        float s0 = -INFINITY, s1 = -INFINITY;
        int c = 0;
        if (e < end) {
            float2 ea = se[e];
            c = __float_as_int(ea.x);
            const float4 kv = ((const float4*)(k + (size_t)c * DIM))[l32];
            float x = qv.x * kv.x + qv.y * kv.y + qv.z * kv.z + qv.w * kv.w;
            float y = er * eigs[(size_t)c * EIGD + l32];
#pragma unroll
            for (int off = 16; off >= 1; off >>= 1) {
                x += __shfl_xor(x, off);
                y += __shfl_xor(y, off);
            }
            s0 = x * inv_sqrt_d + el0 * y;
            s1 = cs * ea.y;
        }
        // broadcast per-edge scalars to the whole wave
        float s0a = __shfl(s0, 0),  s0b = __shfl(s0, 32);
        float s1a = __shfl(s1, 0),  s1b = __shfl(s1, 32);
        int   ca  = __shfl(c, 0),   cb  = __shfl(c, 32);
        bool hasB = (base + 1 < end);

        float nm0 = fmaxf(m0, fmaxf(s0a, s0b));
        float r0  = expf(m0 - nm0);
        float w0a = expf(s0a - nm0);
        float w0b = hasB ? expf(s0b - nm0) : 0.f;
        z0 = z0 * r0 + w0a + w0b;
        m0 = nm0;

        float nm1 = fmaxf(m1, fmaxf(s1a, s1b));
        float r1  = expf(m1 - nm1);
        float w1a = expf(s1a - nm1);
        float w1b = hasB ? expf(s1b - nm1) : 0.f;
        z1 = z1 * r1 + w1a + w1b;
        m1 = nm1;

        float2 va = ((const float2*)(v + (size_t)ca * DIM))[lane];
        acc0.x = acc0.x * r0 + w0a * va.x; acc0.y = acc0.y * r0 + w0a * va.y;
        acc1.x = acc1.x * r1 + w1a * va.x; acc1.y = acc1.y * r1 + w1a * va.y;
        if (hasB) {
            float2 vb = ((const float2*)(v + (size_t)cb * DIM))[lane];
            acc0.x += w0b * vb.x; acc0.y += w0b * vb.y;
            acc1.x += w1b * vb.x; acc1.y += w1b * vb.y;
        }
    }

    float iz0 = 1.f / z0, iz1 = 1.f / z1;
    float2 o = make_float2(0.5f * (acc0.x * iz0 + acc1.x * iz1),
                           0.5f * (acc0.y * iz0 + acc1.y * iz1));
    ((float2*)(out + (size_t)r * DIM))[lane] = o;
}

extern "C" void kernel_launch(void* const* d_in, const int* in_sizes, int n_in,
                              void* d_out, int out_size, void* d_ws, size_t ws_size,
                              hipStream_t stream) {
    const float* q        = (const float*)d_in[0];
    const float* k        = (const float*)d_in[1];
    const float* v        = (const float*)d_in[2];
    const float* eigs     = (const float*)d_in[3];
    const float* adj      = (const float*)d_in[4];
    const float* lambda0  = (const float*)d_in[5];
    const float* gamma    = (const float*)d_in[6];
    const float* motif_w  = (const float*)d_in[7];
    const int*   row      = (const int*)d_in[8];
    const int*   col      = (const int*)d_in[9];
    const int*   motif_ids= (const int*)d_in[10];
    float* out = (float*)d_out;

    char* ws = (char*)d_ws;
    float2* se     = (float2*)(ws + OFF_SE);
    int*    count  = (int*)(ws + OFF_COUNT);
    int*    offs   = (int*)(ws + OFF_OFFS);
    int*    cursor = (int*)(ws + OFF_CURSOR);
    float*  me     = (float*)(ws + OFF_ME);
    float*  scal   = (float*)(ws + OFF_SCAL);

    hipLaunchKernelGGL(k0_init, dim3((N_NODES + 255) / 256), dim3(256), 0, stream,
                       motif_w, motif_ids, me, count, scal);
    hipLaunchKernelGGL(k1_hist, dim3((N_EDGES + 255) / 256), dim3(256), 0, stream,
                       row, col, me, count, scal);
    hipLaunchKernelGGL(k2_scan, dim3(1), dim3(1024), 0, stream,
                       gamma, scal, count, offs, cursor);
    hipLaunchKernelGGL(k3_scatter, dim3((N_EDGES + 255) / 256), dim3(256), 0, stream,
                       row, col, adj, cursor, se);
    hipLaunchKernelGGL(k4_flash, dim3((N_NODES + 3) / 4), dim3(256), 0, stream,
                       q, k, eigs, v, lambda0, offs, se, scal, out);
}

// Round 3
// 522.203 us; speedup vs baseline: 2.0822x; 2.0822x over previous
//
#include <hip/hip_runtime.h>
#include <math.h>

#define N_NODES 100000
#define N_EDGES 1600000
#define DIM 128
#define EIGD 32
#define CS_EPS 1e-8f

#define B1 256                    // coarse-pass blocks (each owns CHUNK edges)
#define CHUNK 6250                // N_EDGES / B1, exact
#define NB 391                    // ceil(N_NODES/256) coarse buckets of 256 rows

// ---- workspace layout (bytes) ----
static const size_t OFF_REC    = 0;          // E int2 {col|rowlow<<17, adj_bits} coarse-sorted
static const size_t OFF_SE     = 12800000;   // E float2 {col_bits, adj} CSR-ordered
static const size_t OFF_GH     = 25600000;   // B1*NB int
static const size_t OFF_BSTART = 26000384;   // (NB+1) int
static const size_t OFF_GPART  = 26001952;   // B1 float4 (pad)
static const size_t OFF_OFFS   = 26006048;   // N+1 int
static const size_t OFF_SCAL   = 26406064;   // 4 float (c,...)

// Coarse histogram over row>>8 + cosine-sim partial sums. No global atomics.
__global__ void __launch_bounds__(256) kb_hist(
        const int* __restrict__ row, const int* __restrict__ col,
        const float* __restrict__ motif_w, const int* __restrict__ motif_ids,
        int* __restrict__ gh, float4* __restrict__ gpart) {
    __shared__ int hist[NB];
    __shared__ float wlds[64];
    __shared__ float red[3][4];
    const int t = threadIdx.x, b = blockIdx.x;
    for (int i = t; i < NB; i += 256) hist[i] = 0;
    if (t < 64) wlds[t] = motif_w[t];
    __syncthreads();

    const int e0 = b * CHUNK, e1 = min(N_EDGES, e0 + CHUNK);
    float sab = 0.f, saa = 0.f, sbb = 0.f;
    for (int e = e0 + t; e < e1; e += 256) {
        int r = row[e], c = col[e];
        atomicAdd(&hist[r >> 8], 1);
        float mr = wlds[motif_ids[r]], mc = wlds[motif_ids[c]];
        sab += mr * mc; saa += mr * mr; sbb += mc * mc;
    }
#pragma unroll
    for (int off = 32; off >= 1; off >>= 1) {
        sab += __shfl_xor(sab, off);
        saa += __shfl_xor(saa, off);
        sbb += __shfl_xor(sbb, off);
    }
    int lane = t & 63, wid = t >> 6;
    if (lane == 0) { red[0][wid] = sab; red[1][wid] = saa; red[2][wid] = sbb; }
    __syncthreads();
    if (t == 0) {
        float a = 0.f, bb = 0.f, cc = 0.f;
#pragma unroll
        for (int i = 0; i < 4; i++) { a += red[0][i]; bb += red[1][i]; cc += red[2][i]; }
        gpart[b] = make_float4(a, bb, cc, 0.f);
    }
    __syncthreads();
    for (int i = t; i < NB; i += 256) gh[b * NB + i] = hist[i];
}

// One block: per-bucket exclusive scan of gh columns (in place), bucket starts,
// cosine scalar c = gamma * sim, offs[N]=E.
__global__ void __launch_bounds__(512) ke_scan(
        int* __restrict__ gh, int* __restrict__ bstart,
        const float4* __restrict__ gpart, const float* __restrict__ gamma,
        float* __restrict__ scal, int* __restrict__ offs) {
    const int t = threadIdx.x;
    __shared__ int tot[512];
    int mytot = 0;
    if (t < NB) {
        int run = 0;
        for (int b = 0; b < B1; b++) {
            int v = gh[b * NB + t];
            gh[b * NB + t] = run;
            run += v;
        }
        mytot = run;
    }
    tot[t] = mytot;
    __syncthreads();
    for (int off = 1; off < 512; off <<= 1) {
        int v = (t >= off) ? tot[t - off] : 0;
        __syncthreads();
        tot[t] += v;
        __syncthreads();
    }
    if (t < NB) bstart[t] = tot[t] - mytot;
    if (t == NB - 1) {
        bstart[NB] = tot[t];
        offs[N_NODES] = tot[t];
    }

    // cosine scalar
    float sab = 0.f, saa = 0.f, sbb = 0.f;
    for (int i = t; i < B1; i += 512) {
        float4 g = gpart[i];
        sab += g.x; saa += g.y; sbb += g.z;
    }
#pragma unroll
    for (int off = 32; off >= 1; off >>= 1) {
        sab += __shfl_xor(sab, off);
        saa += __shfl_xor(saa, off);
        sbb += __shfl_xor(sbb, off);
    }
    __shared__ float red[3][8];
    int lane = t & 63, wid = t >> 6;
    if (lane == 0) { red[0][wid] = sab; red[1][wid] = saa; red[2][wid] = sbb; }
    __syncthreads();
    if (t == 0) {
        float a = 0.f, bb = 0.f, cc = 0.f;
#pragma unroll
        for (int i = 0; i < 8; i++) { a += red[0][i]; bb += red[1][i]; cc += red[2][i]; }
        float na = sqrtf(bb); if (na < CS_EPS) na = CS_EPS;
        float nb2 = sqrtf(cc); if (nb2 < CS_EPS) nb2 = CS_EPS;
        scal[0] = gamma[0] * (a / (na * nb2));
    }
}

// Coarse scatter into bucket-sorted records; LDS cursors only.
__global__ void __launch_bounds__(256) kd_coarse(
        const int* __restrict__ row, const int* __restrict__ col,
        const float* __restrict__ adj, const int* __restrict__ gh,
        const int* __restrict__ bstart, int2* __restrict__ rec) {
    __shared__ int cur[NB];
    const int t = threadIdx.x, b = blockIdx.x;
    for (int i = t; i < NB; i += 256) cur[i] = bstart[i] + gh[b * NB + i];
    __syncthreads();
    const int e0 = b * CHUNK, e1 = min(N_EDGES, e0 + CHUNK);
    for (int e = e0 + t; e < e1; e += 256) {
        int r = row[e];
        int pos = atomicAdd(&cur[r >> 8], 1);
        rec[pos] = make_int2(col[e] | ((r & 255) << 17), __float_as_int(adj[e]));
    }
}

// Fine sort within each bucket (256 rows): offs + final CSR se.
__global__ void __launch_bounds__(256) kf_fine(
        const int2* __restrict__ rec, const int* __restrict__ bstart,
        int* __restrict__ offs, float2* __restrict__ se) {
    __shared__ int hist[256], sc[256], cur[256];
    const int t = threadIdx.x, b = blockIdx.x;
    hist[t] = 0;
    __syncthreads();
    const int s = bstart[b], e1 = bstart[b + 1];
    for (int i = s + t; i < e1; i += 256) {
        int rl = (rec[i].x >> 17) & 255;
        atomicAdd(&hist[rl], 1);
    }
    __syncthreads();
    int v = hist[t];
    sc[t] = v;
    __syncthreads();
    for (int off = 1; off < 256; off <<= 1) {
        int w = (t >= off) ? sc[t - off] : 0;
        __syncthreads();
        sc[t] += w;
        __syncthreads();
    }
    int excl = sc[t] - v;
    int rowg = b * 256 + t;
    if (rowg < N_NODES) offs[rowg] = s + excl;
    cur[t] = s + excl;
    __syncthreads();
    for (int i = s + t; i < e1; i += 256) {
        int2 rc = rec[i];
        int rl = (rc.x >> 17) & 255;
        int pos = atomicAdd(&cur[rl], 1);
        se[pos] = make_float2(__int_as_float(rc.x & 0x1FFFF), __int_as_float(rc.y));
    }
}

// Fused flash-style per-row attention: one wave per row.
__global__ void __launch_bounds__(256) k4_flash(
        const float* __restrict__ q, const float* __restrict__ k,
        const float* __restrict__ eigs, const float* __restrict__ v,
        const float* __restrict__ lambda0, const int* __restrict__ offs,
        const float2* __restrict__ se, const float* __restrict__ scal,
        float* __restrict__ out) {
    const int tid  = threadIdx.x;
    const int lane = tid & 63;
    const int wid  = tid >> 6;
    const int r = blockIdx.x * 4 + wid;
    if (r >= N_NODES) return;
    const int l32  = lane & 31;
    const int half = lane >> 5;
    const float inv_sqrt_d = 0.08838834764831843f; // 1/sqrt(128)

    const int start = offs[r], end = offs[r + 1];
    if (end == start) {
        ((float2*)(out + (size_t)r * DIM))[lane] = make_float2(0.f, 0.f);
        return;
    }

    const float el0 = expf(lambda0[0]);
    const float cs  = scal[0];

    const float4 qv = ((const float4*)(q + (size_t)r * DIM))[l32];
    const float  er = eigs[(size_t)r * EIGD + l32];

    float m0 = -INFINITY, z0 = 0.f, m1 = -INFINITY, z1 = 0.f;
    float2 acc0 = make_float2(0.f, 0.f), acc1 = make_float2(0.f, 0.f);

    for (int base = start; base < end; base += 2) {
        int e = base + half;              // uniform per 32-lane group
        float s0 = -INFINITY, s1 = -INFINITY;
        int c = 0;
        if (e < end) {
            float2 ea = se[e];
            c = __float_as_int(ea.x);
            const float4 kv = ((const float4*)(k + (size_t)c * DIM))[l32];
            float x = qv.x * kv.x + qv.y * kv.y + qv.z * kv.z + qv.w * kv.w;
            float y = er * eigs[(size_t)c * EIGD + l32];
#pragma unroll
            for (int off = 16; off >= 1; off >>= 1) {
                x += __shfl_xor(x, off);
                y += __shfl_xor(y, off);
            }
            s0 = x * inv_sqrt_d + el0 * y;
            s1 = cs * ea.y;
        }
        float s0a = __shfl(s0, 0),  s0b = __shfl(s0, 32);
        float s1a = __shfl(s1, 0),  s1b = __shfl(s1, 32);
        int   ca  = __shfl(c, 0),   cb  = __shfl(c, 32);
        bool hasB = (base + 1 < end);

        float nm0 = fmaxf(m0, fmaxf(s0a, s0b));
        float r0  = __expf(m0 - nm0);
        float w0a = __expf(s0a - nm0);
        float w0b = hasB ? __expf(s0b - nm0) : 0.f;
        z0 = z0 * r0 + w0a + w0b;
        m0 = nm0;

        float nm1 = fmaxf(m1, fmaxf(s1a, s1b));
        float r1  = __expf(m1 - nm1);
        float w1a = __expf(s1a - nm1);
        float w1b = hasB ? __expf(s1b - nm1) : 0.f;
        z1 = z1 * r1 + w1a + w1b;
        m1 = nm1;

        float2 va = ((const float2*)(v + (size_t)ca * DIM))[lane];
        acc0.x = acc0.x * r0 + w0a * va.x; acc0.y = acc0.y * r0 + w0a * va.y;
        acc1.x = acc1.x * r1 + w1a * va.x; acc1.y = acc1.y * r1 + w1a * va.y;
        if (hasB) {
            float2 vb = ((const float2*)(v + (size_t)cb * DIM))[lane];
            acc0.x += w0b * vb.x; acc0.y += w0b * vb.y;
            acc1.x += w1b * vb.x; acc1.y += w1b * vb.y;
        }
    }

    float iz0 = 1.f / z0, iz1 = 1.f / z1;
    float2 o = make_float2(0.5f * (acc0.x * iz0 + acc1.x * iz1),
                           0.5f * (acc0.y * iz0 + acc1.y * iz1));
    ((float2*)(out + (size_t)r * DIM))[lane] = o;
}

extern "C" void kernel_launch(void* const* d_in, const int* in_sizes, int n_in,
                              void* d_out, int out_size, void* d_ws, size_t ws_size,
                              hipStream_t stream) {
    const float* q        = (const float*)d_in[0];
    const float* k        = (const float*)d_in[1];
    const float* v        = (const float*)d_in[2];
    const float* eigs     = (const float*)d_in[3];
    const float* adj      = (const float*)d_in[4];
    const float* lambda0  = (const float*)d_in[5];
    const float* gamma    = (const float*)d_in[6];
    const float* motif_w  = (const float*)d_in[7];
    const int*   row      = (const int*)d_in[8];
    const int*   col      = (const int*)d_in[9];
    const int*   motif_ids= (const int*)d_in[10];
    float* out = (float*)d_out;

    char* ws = (char*)d_ws;
    int2*   rec    = (int2*)(ws + OFF_REC);
    float2* se     = (float2*)(ws + OFF_SE);
    int*    gh     = (int*)(ws + OFF_GH);
    int*    bstart = (int*)(ws + OFF_BSTART);
    float4* gpart  = (float4*)(ws + OFF_GPART);
    int*    offs   = (int*)(ws + OFF_OFFS);
    float*  scal   = (float*)(ws + OFF_SCAL);

    hipLaunchKernelGGL(kb_hist, dim3(B1), dim3(256), 0, stream,
                       row, col, motif_w, motif_ids, gh, gpart);
    hipLaunchKernelGGL(ke_scan, dim3(1), dim3(512), 0, stream,
                       gh, bstart, gpart, gamma, scal, offs);
    hipLaunchKernelGGL(kd_coarse, dim3(B1), dim3(256), 0, stream,
                       row, col, adj, gh, bstart, rec);
    hipLaunchKernelGGL(kf_fine, dim3(NB), dim3(256), 0, stream,
                       rec, bstart, offs, se);
    hipLaunchKernelGGL(k4_flash, dim3((N_NODES + 3) / 4), dim3(256), 0, stream,
                       q, k, eigs, v, lambda0, offs, se, scal, out);
}

// Round 4
// 477.612 us; speedup vs baseline: 2.2766x; 1.0934x over previous
//
#include <hip/hip_runtime.h>
#include <math.h>

#define N_NODES 100000
#define N_EDGES 1600000
#define DIM 128
#define EIGD 32
#define CS_EPS 1e-8f

#define B1 256                    // coarse-pass blocks (each owns CHUNK edges)
#define CHUNK 6250                // N_EDGES / B1, exact
#define NB 391                    // ceil(N_NODES/256) coarse buckets of 256 rows

// ---- workspace layout (bytes) ----
static const size_t OFF_REC    = 0;          // E int2 coarse-sorted records
static const size_t OFF_SE     = 12800000;   // E float2 {col_bits, adj} CSR-ordered
static const size_t OFF_GH     = 25600000;   // B1*NB int
static const size_t OFF_BSTART = 26000384;   // (NB+1) int
static const size_t OFF_GPART  = 26001952;   // B1 float4
static const size_t OFF_OFFS   = 26006048;   // N+1 int (padded)
static const size_t OFF_SCAL   = 26406064;   // 4 float
static const size_t OFF_KB     = 26406080;   // N*128 bf16 = 25.6 MB
static const size_t OFF_VB     = 52006080;   // N*128 bf16 = 25.6 MB
static const size_t OFF_EB     = 77606080;   // N*32  bf16 = 6.4 MB
// total ~84 MB

__device__ __forceinline__ unsigned short f2bf(float f) {
    unsigned u = __float_as_uint(f);
    unsigned r = (u + 0x7fffu + ((u >> 16) & 1u)) >> 16;   // RNE
    return (unsigned short)r;
}
__device__ __forceinline__ float blo(unsigned w) { return __uint_as_float(w << 16); }
__device__ __forceinline__ float bhi(unsigned w) { return __uint_as_float(w & 0xffff0000u); }

#define K4C 3200000   // N*128/4 float4s in k (and v)
#define E4C 800000    // N*32/4  float4s in eigs

// Convert k, v, eigs to bf16 staging arrays (halves gather line traffic).
__global__ void __launch_bounds__(256) ka_cvt(
        const float* __restrict__ k, const float* __restrict__ v,
        const float* __restrict__ eigs,
        ushort* __restrict__ kb, ushort* __restrict__ vb,
        ushort* __restrict__ eb) {
    int i = blockIdx.x * blockDim.x + threadIdx.x;
    const float* src; ushort* dst; int j;
    if (i < K4C)            { src = k;    dst = kb; j = i; }
    else if (i < 2 * K4C)   { src = v;    dst = vb; j = i - K4C; }
    else if (i < 2*K4C+E4C) { src = eigs; dst = eb; j = i - 2 * K4C; }
    else return;
    float4 f = ((const float4*)src)[j];
    ushort4 o;
    o.x = f2bf(f.x); o.y = f2bf(f.y); o.z = f2bf(f.z); o.w = f2bf(f.w);
    ((ushort4*)dst)[j] = o;
}

// Coarse histogram over row>>8 + cosine-sim partial sums. No global atomics.
__global__ void __launch_bounds__(256) kb_hist(
        const int* __restrict__ row, const int* __restrict__ col,
        const float* __restrict__ motif_w, const int* __restrict__ motif_ids,
        int* __restrict__ gh, float4* __restrict__ gpart) {
    __shared__ int hist[NB];
    __shared__ float wlds[64];
    __shared__ float red[3][4];
    const int t = threadIdx.x, b = blockIdx.x;
    for (int i = t; i < NB; i += 256) hist[i] = 0;
    if (t < 64) wlds[t] = motif_w[t];
    __syncthreads();

    const int e0 = b * CHUNK, e1 = min(N_EDGES, e0 + CHUNK);
    float sab = 0.f, saa = 0.f, sbb = 0.f;
    for (int e = e0 + t; e < e1; e += 256) {
        int r = row[e], c = col[e];
        atomicAdd(&hist[r >> 8], 1);
        float mr = wlds[motif_ids[r]], mc = wlds[motif_ids[c]];
        sab += mr * mc; saa += mr * mr; sbb += mc * mc;
    }
#pragma unroll
    for (int off = 32; off >= 1; off >>= 1) {
        sab += __shfl_xor(sab, off);
        saa += __shfl_xor(saa, off);
        sbb += __shfl_xor(sbb, off);
    }
    int lane = t & 63, wid = t >> 6;
    if (lane == 0) { red[0][wid] = sab; red[1][wid] = saa; red[2][wid] = sbb; }
    __syncthreads();
    if (t == 0) {
        float a = 0.f, bb = 0.f, cc = 0.f;
#pragma unroll
        for (int i = 0; i < 4; i++) { a += red[0][i]; bb += red[1][i]; cc += red[2][i]; }
        gpart[b] = make_float4(a, bb, cc, 0.f);
    }
    __syncthreads();
    for (int i = t; i < NB; i += 256) gh[b * NB + i] = hist[i];
}

// One block: per-bucket exclusive scan of gh columns, bucket starts, cosine c.
__global__ void __launch_bounds__(512) ke_scan(
        int* __restrict__ gh, int* __restrict__ bstart,
        const float4* __restrict__ gpart, const float* __restrict__ gamma,
        float* __restrict__ scal, int* __restrict__ offs) {
    const int t = threadIdx.x;
    __shared__ int tot[512];
    int mytot = 0;
    if (t < NB) {
        int run = 0;
        for (int b = 0; b < B1; b++) {
            int v = gh[b * NB + t];
            gh[b * NB + t] = run;
            run += v;
        }
        mytot = run;
    }
    tot[t] = mytot;
    __syncthreads();
    for (int off = 1; off < 512; off <<= 1) {
        int v = (t >= off) ? tot[t - off] : 0;
        __syncthreads();
        tot[t] += v;
        __syncthreads();
    }
    if (t < NB) bstart[t] = tot[t] - mytot;
    if (t == NB - 1) {
        bstart[NB] = tot[t];
        offs[N_NODES] = tot[t];
    }

    float sab = 0.f, saa = 0.f, sbb = 0.f;
    for (int i = t; i < B1; i += 512) {
        float4 g = gpart[i];
        sab += g.x; saa += g.y; sbb += g.z;
    }
#pragma unroll
    for (int off = 32; off >= 1; off >>= 1) {
        sab += __shfl_xor(sab, off);
        saa += __shfl_xor(saa, off);
        sbb += __shfl_xor(sbb, off);
    }
    __shared__ float red[3][8];
    int lane = t & 63, wid = t >> 6;
    if (lane == 0) { red[0][wid] = sab; red[1][wid] = saa; red[2][wid] = sbb; }
    __syncthreads();
    if (t == 0) {
        float a = 0.f, bb = 0.f, cc = 0.f;
#pragma unroll
        for (int i = 0; i < 8; i++) { a += red[0][i]; bb += red[1][i]; cc += red[2][i]; }
        float na = sqrtf(bb); if (na < CS_EPS) na = CS_EPS;
        float nb2 = sqrtf(cc); if (nb2 < CS_EPS) nb2 = CS_EPS;
        scal[0] = gamma[0] * (a / (na * nb2));
    }
}

// Coarse scatter into bucket-sorted records; LDS cursors only.
__global__ void __launch_bounds__(256) kd_coarse(
        const int* __restrict__ row, const int* __restrict__ col,
        const float* __restrict__ adj, const int* __restrict__ gh,
        const int* __restrict__ bstart, int2* __restrict__ rec) {
    __shared__ int cur[NB];
    const int t = threadIdx.x, b = blockIdx.x;
    for (int i = t; i < NB; i += 256) cur[i] = bstart[i] + gh[b * NB + i];
    __syncthreads();
    const int e0 = b * CHUNK, e1 = min(N_EDGES, e0 + CHUNK);
    for (int e = e0 + t; e < e1; e += 256) {
        int r = row[e];
        int pos = atomicAdd(&cur[r >> 8], 1);
        rec[pos] = make_int2(col[e] | ((r & 255) << 17), __float_as_int(adj[e]));
    }
}

// Fine sort within each bucket (256 rows): offs + final CSR se.
__global__ void __launch_bounds__(256) kf_fine(
        const int2* __restrict__ rec, const int* __restrict__ bstart,
        int* __restrict__ offs, float2* __restrict__ se) {
    __shared__ int hist[256], sc[256], cur[256];
    const int t = threadIdx.x, b = blockIdx.x;
    hist[t] = 0;
    __syncthreads();
    const int s = bstart[b], e1 = bstart[b + 1];
    for (int i = s + t; i < e1; i += 256) {
        int rl = (rec[i].x >> 17) & 255;
        atomicAdd(&hist[rl], 1);
    }
    __syncthreads();
    int v = hist[t];
    sc[t] = v;
    __syncthreads();
    for (int off = 1; off < 256; off <<= 1) {
        int w = (t >= off) ? sc[t - off] : 0;
        __syncthreads();
        sc[t] += w;
        __syncthreads();
    }
    int excl = sc[t] - v;
    int rowg = b * 256 + t;
    if (rowg < N_NODES) offs[rowg] = s + excl;
    cur[t] = s + excl;
    __syncthreads();
    for (int i = s + t; i < e1; i += 256) {
        int2 rc = rec[i];
        int rl = (rc.x >> 17) & 255;
        int pos = atomicAdd(&cur[rl], 1);
        se[pos] = make_float2(__int_as_float(rc.x & 0x1FFFF), __int_as_float(rc.y));
    }
}

// Fused flash attention: one wave per row, 4 edges/iter, 16-lane dot groups,
// bf16 k/v/eig gathers (half the cache-line traffic of fp32).
__global__ void __launch_bounds__(256) k4_flash(
        const float* __restrict__ q, const ushort* __restrict__ kb,
        const ushort* __restrict__ eb, const ushort* __restrict__ vb,
        const float* __restrict__ lambda0, const int* __restrict__ offs,
        const float2* __restrict__ se, const float* __restrict__ scal,
        float* __restrict__ out) {
    const int tid  = threadIdx.x;
    const int lane = tid & 63;
    const int wid  = tid >> 6;
    const int r = blockIdx.x * 4 + wid;
    if (r >= N_NODES) return;
    const int l16 = lane & 15;
    const int grp = lane >> 4;
    const float inv_sqrt_d = 0.08838834764831843f; // 1/sqrt(128)

    const int start = offs[r], end = offs[r + 1];
    if (end == start) {
        ((float2*)(out + (size_t)r * DIM))[lane] = make_float2(0.f, 0.f);
        return;
    }

    const float el0 = expf(lambda0[0]);
    const float cs  = scal[0];

    // q dims [l16*8, l16*8+8) in registers (fp32)
    const float4* qp = (const float4*)(q + (size_t)r * DIM);
    const float4 qa = qp[l16 * 2];
    const float4 qc = qp[l16 * 2 + 1];
    // eig dims [l16*2, l16*2+1] (bf16 -> fp32)
    const unsigned erw = *(const unsigned*)(eb + (size_t)r * EIGD + l16 * 2);
    const float er0 = blo(erw), er1 = bhi(erw);

    float m0 = -INFINITY, z0 = 0.f, m1 = -INFINITY, z1 = 0.f;
    float2 acc0 = make_float2(0.f, 0.f), acc1 = make_float2(0.f, 0.f);

    for (int base = start; base < end; base += 4) {
        int e = base + grp;
        float s0p = -INFINITY, s1v = -INFINITY;
        int c = 0;
        if (e < end) {
            float2 ea = se[e];
            c = __float_as_int(ea.x);
            s1v = cs * ea.y;
            const uint4 kw = *(const uint4*)(kb + (size_t)c * DIM + l16 * 8);
            float x;
            x = qa.x * blo(kw.x);
            x = fmaf(qa.y, bhi(kw.x), x);
            x = fmaf(qa.z, blo(kw.y), x);
            x = fmaf(qa.w, bhi(kw.y), x);
            x = fmaf(qc.x, blo(kw.z), x);
            x = fmaf(qc.y, bhi(kw.z), x);
            x = fmaf(qc.z, blo(kw.w), x);
            x = fmaf(qc.w, bhi(kw.w), x);
            const unsigned ecw = *(const unsigned*)(eb + (size_t)c * EIGD + l16 * 2);
            float y = er0 * blo(ecw) + er1 * bhi(ecw);
            s0p = x * inv_sqrt_d + el0 * y;   // pre-scaled partial
        }
        // butterfly within each 16-lane group (invalid groups stay -inf)
#pragma unroll
        for (int off = 8; off >= 1; off >>= 1) s0p += __shfl_xor(s0p, off);

        float s00 = __shfl(s0p, 0),  s01 = __shfl(s0p, 16);
        float s02 = __shfl(s0p, 32), s03 = __shfl(s0p, 48);
        float s10 = __shfl(s1v, 0),  s11 = __shfl(s1v, 16);
        float s12 = __shfl(s1v, 32), s13 = __shfl(s1v, 48);
        int   c0  = __shfl(c, 0),    c1  = __shfl(c, 16);
        int   c2  = __shfl(c, 32),   c3  = __shfl(c, 48);
        int cnt = end - base;

        float nm0 = fmaxf(m0, fmaxf(fmaxf(s00, s01), fmaxf(s02, s03)));
        float r0  = __expf(m0 - nm0);          // m0=-inf first iter -> 0
        float w00 = __expf(s00 - nm0);
        float w01 = __expf(s01 - nm0);         // -inf -> 0 for invalid
        float w02 = __expf(s02 - nm0);
        float w03 = __expf(s03 - nm0);
        z0 = z0 * r0 + w00 + w01 + w02 + w03;
        m0 = nm0;

        float nm1 = fmaxf(m1, fmaxf(fmaxf(s10, s11), fmaxf(s12, s13)));
        float r1  = __expf(m1 - nm1);
        float w10 = __expf(s10 - nm1);
        float w11 = __expf(s11 - nm1);
        float w12 = __expf(s12 - nm1);
        float w13 = __expf(s13 - nm1);
        z1 = z1 * r1 + w10 + w11 + w12 + w13;
        m1 = nm1;

        acc0.x *= r0; acc0.y *= r0;
        acc1.x *= r1; acc1.y *= r1;
        {
            unsigned vw = *(const unsigned*)(vb + (size_t)c0 * DIM + lane * 2);
            float vx = blo(vw), vy = bhi(vw);
            acc0.x = fmaf(w00, vx, acc0.x); acc0.y = fmaf(w00, vy, acc0.y);
            acc1.x = fmaf(w10, vx, acc1.x); acc1.y = fmaf(w10, vy, acc1.y);
        }
        if (cnt > 1) {
            unsigned vw = *(const unsigned*)(vb + (size_t)c1 * DIM + lane * 2);
            float vx = blo(vw), vy = bhi(vw);
            acc0.x = fmaf(w01, vx, acc0.x); acc0.y = fmaf(w01, vy, acc0.y);
            acc1.x = fmaf(w11, vx, acc1.x); acc1.y = fmaf(w11, vy, acc1.y);
        }
        if (cnt > 2) {
            unsigned vw = *(const unsigned*)(vb + (size_t)c2 * DIM + lane * 2);
            float vx = blo(vw), vy = bhi(vw);
            acc0.x = fmaf(w02, vx, acc0.x); acc0.y = fmaf(w02, vy, acc0.y);
            acc1.x = fmaf(w12, vx, acc1.x); acc1.y = fmaf(w12, vy, acc1.y);
        }
        if (cnt > 3) {
            unsigned vw = *(const unsigned*)(vb + (size_t)c3 * DIM + lane * 2);
            float vx = blo(vw), vy = bhi(vw);
            acc0.x = fmaf(w03, vx, acc0.x); acc0.y = fmaf(w03, vy, acc0.y);
            acc1.x = fmaf(w13, vx, acc1.x); acc1.y = fmaf(w13, vy, acc1.y);
        }
    }

    float iz0 = 1.f / z0, iz1 = 1.f / z1;
    float2 o = make_float2(0.5f * (acc0.x * iz0 + acc1.x * iz1),
                           0.5f * (acc0.y * iz0 + acc1.y * iz1));
    ((float2*)(out + (size_t)r * DIM))[lane] = o;
}

extern "C" void kernel_launch(void* const* d_in, const int* in_sizes, int n_in,
                              void* d_out, int out_size, void* d_ws, size_t ws_size,
                              hipStream_t stream) {
    const float* q        = (const float*)d_in[0];
    const float* k        = (const float*)d_in[1];
    const float* v        = (const float*)d_in[2];
    const float* eigs     = (const float*)d_in[3];
    const float* adj      = (const float*)d_in[4];
    const float* lambda0  = (const float*)d_in[5];
    const float* gamma    = (const float*)d_in[6];
    const float* motif_w  = (const float*)d_in[7];
    const int*   row      = (const int*)d_in[8];
    const int*   col      = (const int*)d_in[9];
    const int*   motif_ids= (const int*)d_in[10];
    float* out = (float*)d_out;

    char* ws = (char*)d_ws;
    int2*   rec    = (int2*)(ws + OFF_REC);
    float2* se     = (float2*)(ws + OFF_SE);
    int*    gh     = (int*)(ws + OFF_GH);
    int*    bstart = (int*)(ws + OFF_BSTART);
    float4* gpart  = (float4*)(ws + OFF_GPART);
    int*    offs   = (int*)(ws + OFF_OFFS);
    float*  scal   = (float*)(ws + OFF_SCAL);
    ushort* kb     = (ushort*)(ws + OFF_KB);
    ushort* vb     = (ushort*)(ws + OFF_VB);
    ushort* eb     = (ushort*)(ws + OFF_EB);

    hipLaunchKernelGGL(ka_cvt, dim3((2 * K4C + E4C + 255) / 256), dim3(256), 0, stream,
                       k, v, eigs, kb, vb, eb);
    hipLaunchKernelGGL(kb_hist, dim3(B1), dim3(256), 0, stream,
                       row, col, motif_w, motif_ids, gh, gpart);
    hipLaunchKernelGGL(ke_scan, dim3(1), dim3(512), 0, stream,
                       gh, bstart, gpart, gamma, scal, offs);
    hipLaunchKernelGGL(kd_coarse, dim3(B1), dim3(256), 0, stream,
                       row, col, adj, gh, bstart, rec);
    hipLaunchKernelGGL(kf_fine, dim3(NB), dim3(256), 0, stream,
                       rec, bstart, offs, se);
    hipLaunchKernelGGL(k4_flash, dim3((N_NODES + 3) / 4), dim3(256), 0, stream,
                       q, kb, eb, vb, lambda0, offs, se, scal, out);
}